// Round 3
// baseline (650.108 us; speedup 1.0000x reference)
//
#include <hip/hip_runtime.h>
#include <cmath>

#define NTOK 65536
#define DMOD 1024
#define NEXP 64
#define TOPK 8

// token_mask may arrive as 1-byte bool or int32; sniff from the first word.
// (all-true byte-bool => 0x01010101; int32 true => 0x00000001; float 1.0f also != 0)
__device__ __forceinline__ bool tok_mask(const void* tm, int t, int mmode) {
    return mmode == 0 ? (((const unsigned char*)tm)[t] != 0)
                      : (((const unsigned int*)tm)[t] != 0u);
}

__global__ __launch_bounds__(256)
void router_seqfma(const float* __restrict__ h,
                   const float* __restrict__ W,
                   const void* __restrict__ tmask,
                   float* __restrict__ out)
{
    __shared__ float ls[64][65];              // fp32 logits tile (+1 pad)
    __shared__ float pb[64][65];              // probs tile
    __shared__ unsigned long long mb[64];     // selection bitmask per token

    const int tid  = threadIdx.x;
    const int lane = tid & 63;
    const int wave = tid >> 6;
    const int t0   = blockIdx.x * 64;
    const int eb   = wave * 16;               // this wave's expert base

    const unsigned int w0 = *(const unsigned int*)tmask;
    const int mmode = (w0 == 0x01010101u) ? 0 : 1;

    const float* __restrict__ hrow = h + (size_t)(t0 + lane) * DMOD;

    // ---- K loop: STRICTLY SEQUENTIAL fp32 FMA over k = 0..1023 (BLAS order) ----
    float acc[16];
#pragma unroll
    for (int e = 0; e < 16; ++e) acc[e] = 0.f;

    for (int k = 0; k < DMOD; k += 4) {
        const float4 hv = *reinterpret_cast<const float4*>(hrow + k);
#pragma unroll
        for (int e = 0; e < 16; ++e) {
            const float4 wv = *reinterpret_cast<const float4*>(W + (size_t)(eb + e) * DMOD + k);
            float a = acc[e];
            a = fmaf(hv.x, wv.x, a);
            a = fmaf(hv.y, wv.y, a);
            a = fmaf(hv.z, wv.z, a);
            a = fmaf(hv.w, wv.w, a);
            acc[e] = a;
        }
    }

#pragma unroll
    for (int j = 0; j < 16; ++j) ls[lane][eb + j] = acc[j];

    __syncthreads();

    const size_t P = (size_t)NTOK * NEXP;
    float* __restrict__ o_mask = out;
    float* __restrict__ o_prob = out + P;
    float* __restrict__ o_lc   = out + 2 * P;
    float* __restrict__ o_lsl  = out + 3 * P;
    const size_t base = (size_t)t0 * NEXP;

    // ---- coalesced writes of logits_clean / logits_sel (same fp32 bits as selection) ----
#pragma unroll
    for (int i = 0; i < 16; ++i) {
        const int f = i * 256 + tid;
        const int t = f >> 6, e = f & 63;
        const float lv = ls[t][e];
        const bool tmt = tok_mask(tmask, t0 + t, mmode);
        o_lc[base + f]  = lv;
        o_lsl[base + f] = tmt ? lv : -INFINITY;
    }

    // ---- epilogue: wave0, one token per lane; 8-pass selection-sort top-k ----
    // strict '>' comparison => lower index wins on exact ties (lax.top_k semantics)
    if (wave == 0) {
        const int lt = lane;
        const bool tm = tok_mask(tmask, t0 + lt, mmode);

        unsigned long long bits = 0ULL;
        float m0 = -INFINITY;
        for (int r = 0; r < TOPK; ++r) {
            float bv = -INFINITY; int bi = 0;
            for (int e = 0; e < 64; ++e) {
                if ((bits >> e) & 1ULL) continue;
                const float x = ls[lt][e];
                if (x > bv) { bv = x; bi = e; }
            }
            bits |= 1ULL << bi;
            if (r == 0) m0 = bv;              // global max
        }

        float ssum = 0.f;
        for (int e = 0; e < 64; ++e)
            if ((bits >> e) & 1ULL) ssum += expf(ls[lt][e] - m0);
        const float inv = 1.0f / ssum;
        for (int e = 0; e < 64; ++e) {
            const bool sel = ((bits >> e) & 1ULL) != 0ULL;
            pb[lt][e] = (tm && sel) ? expf(ls[lt][e] - m0) * inv : 0.f;
        }
        mb[lt] = tm ? bits : 0ULL;
    }

    __syncthreads();

    // ---- coalesced writes of probs / mask ----
#pragma unroll
    for (int i = 0; i < 16; ++i) {
        const int f = i * 256 + tid;
        const int t = f >> 6, e = f & 63;
        o_prob[base + f] = pb[t][e];
        o_mask[base + f] = (float)((mb[t] >> e) & 1ULL);
    }
}

extern "C" void kernel_launch(void* const* d_in, const int* in_sizes, int n_in,
                              void* d_out, int out_size, void* d_ws, size_t ws_size,
                              hipStream_t stream)
{
    const float* h = (const float*)d_in[0];
    const float* W = (const float*)d_in[1];
    const void*  tmask = (const void*)d_in[2];
    float* out = (float*)d_out;

    hipLaunchKernelGGL(router_seqfma, dim3(NTOK / 64), dim3(256), 0, stream,
                       h, W, tmask, out);
}

// Round 4
// 604.227 us; speedup vs baseline: 1.0759x; 1.0759x over previous
//
#include <hip/hip_runtime.h>
#include <cmath>

#define NTOK 65536
#define DMOD 1024
#define NEXP 64
#define TOPK 8
#define KCH  128                 // k-chunk staged in LDS
#define HSTR 132                 // h tile row stride (floats): 33*16B -> uniform 8 lanes/bank

// token_mask may arrive as 1-byte bool or int32; sniff from the first word.
__device__ __forceinline__ bool tok_mask(const void* tm, int t, int mmode) {
    return mmode == 0 ? (((const unsigned char*)tm)[t] != 0)
                      : (((const unsigned int*)tm)[t] != 0u);
}

__global__ __launch_bounds__(256, 3)
void router_seqfma2(const float* __restrict__ h,
                    const float* __restrict__ W,
                    const void* __restrict__ tmask,
                    float* __restrict__ out)
{
    __shared__ float h_lds[64][HSTR];         // 33.8 KB; pb aliased here after compute
    __shared__ float ls[64][65];              // fp32 logits tile (+1 pad)
    __shared__ unsigned long long mb[64];     // selection bitmask per token

    const int tid  = threadIdx.x;
    const int lane = tid & 63;
    const int wave = __builtin_amdgcn_readfirstlane(tid >> 6);  // wave-uniform
    const int t0   = blockIdx.x * 64;
    const int eb   = wave * 16;               // this wave's expert base (uniform)

    const unsigned int w0 = *(const unsigned int*)tmask;
    const int mmode = (w0 == 0x01010101u) ? 0 : 1;

    // ---- accumulators: STRICT sequential fp32 FMA over k=0..1023 (same order as round 3) ----
    float acc[16];
#pragma unroll
    for (int e = 0; e < 16; ++e) acc[e] = 0.f;

    for (int kc = 0; kc < DMOD; kc += KCH) {
        // ---- stage h tile: 64 tokens x 128 k, coalesced global -> LDS ----
#pragma unroll
        for (int p = 0; p < 8; ++p) {
            const int row = p * 8 + (tid >> 5);
            const int c   = (tid & 31) * 4;
            const float4 v = *reinterpret_cast<const float4*>(
                h + (size_t)(t0 + row) * DMOD + kc + c);
            *reinterpret_cast<float4*>(&h_lds[row][c]) = v;
        }
        __syncthreads();

        // ---- compute: h from LDS (per-lane token), W via scalar loads (uniform) ----
#pragma unroll 4
        for (int k8 = 0; k8 < KCH; k8 += 8) {
            const float4 ha = *reinterpret_cast<const float4*>(&h_lds[lane][k8]);
            const float4 hb = *reinterpret_cast<const float4*>(&h_lds[lane][k8 + 4]);
#pragma unroll
            for (int e = 0; e < 16; ++e) {
                const float* wr = W + ((size_t)(eb + e) << 10) + kc + k8;  // uniform addr
                const float4 wa = *reinterpret_cast<const float4*>(wr);
                const float4 wb = *reinterpret_cast<const float4*>(wr + 4);
                float a = acc[e];
                a = fmaf(ha.x, wa.x, a);
                a = fmaf(ha.y, wa.y, a);
                a = fmaf(ha.z, wa.z, a);
                a = fmaf(ha.w, wa.w, a);
                a = fmaf(hb.x, wb.x, a);
                a = fmaf(hb.y, wb.y, a);
                a = fmaf(hb.z, wb.z, a);
                a = fmaf(hb.w, wb.w, a);
                acc[e] = a;
            }
        }
        __syncthreads();
    }

    // ---- stage logits to LDS ----
#pragma unroll
    for (int j = 0; j < 16; ++j) ls[lane][eb + j] = acc[j];

    __syncthreads();

    const size_t P = (size_t)NTOK * NEXP;
    float* __restrict__ o_mask = out;
    float* __restrict__ o_prob = out + P;
    float* __restrict__ o_lc   = out + 2 * P;
    float* __restrict__ o_lsl  = out + 3 * P;
    const size_t base = (size_t)t0 * NEXP;

    // probs tile aliases the (now dead) h tile
    float (*pb)[65] = reinterpret_cast<float(*)[65]>(&h_lds[0][0]);

    // ---- coalesced writes of logits_clean / logits_sel ----
#pragma unroll
    for (int i = 0; i < 16; ++i) {
        const int f = i * 256 + tid;
        const int t = f >> 6, e = f & 63;
        const float lv = ls[t][e];
        const bool tmt = tok_mask(tmask, t0 + t, mmode);
        o_lc[base + f]  = lv;
        o_lsl[base + f] = tmt ? lv : -INFINITY;
    }

    // ---- epilogue: wave0, one token per lane; 8-pass selection-sort top-k ----
    if (wave == 0) {
        const int lt = lane;
        const bool tm = tok_mask(tmask, t0 + lt, mmode);

        unsigned long long bits = 0ULL;
        float m0 = -INFINITY;
        for (int r = 0; r < TOPK; ++r) {
            float bv = -INFINITY; int bi = 0;
            for (int e = 0; e < 64; ++e) {
                if ((bits >> e) & 1ULL) continue;
                const float x = ls[lt][e];
                if (x > bv) { bv = x; bi = e; }
            }
            bits |= 1ULL << bi;
            if (r == 0) m0 = bv;              // global max
        }

        float ssum = 0.f;
        for (int e = 0; e < 64; ++e)
            if ((bits >> e) & 1ULL) ssum += expf(ls[lt][e] - m0);
        const float inv = 1.0f / ssum;
        for (int e = 0; e < 64; ++e) {
            const bool sel = ((bits >> e) & 1ULL) != 0ULL;
            pb[lt][e] = (tm && sel) ? expf(ls[lt][e] - m0) * inv : 0.f;
        }
        mb[lt] = tm ? bits : 0ULL;
    }

    __syncthreads();

    // ---- coalesced writes of probs / mask ----
#pragma unroll
    for (int i = 0; i < 16; ++i) {
        const int f = i * 256 + tid;
        const int t = f >> 6, e = f & 63;
        o_prob[base + f] = pb[t][e];
        o_mask[base + f] = (float)((mb[t] >> e) & 1ULL);
    }
}

extern "C" void kernel_launch(void* const* d_in, const int* in_sizes, int n_in,
                              void* d_out, int out_size, void* d_ws, size_t ws_size,
                              hipStream_t stream)
{
    const float* h = (const float*)d_in[0];
    const float* W = (const float*)d_in[1];
    const void*  tmask = (const void*)d_in[2];
    float* out = (float*)d_out;

    hipLaunchKernelGGL(router_seqfma2, dim3(NTOK / 64), dim3(256), 0, stream,
                       h, W, tmask, out);
}

// Round 5
// 230.711 us; speedup vs baseline: 2.8178x; 2.6190x over previous
//
#include <hip/hip_runtime.h>
#include <cmath>

#define NTOK 65536
#define DMOD 1024
#define NEXP 64
#define TOPK 8
#define KCH  64                  // k-chunk staged in LDS
#define STR  65                  // LDS row stride (floats); 4-row lane stride -> all 32 banks

// token_mask may arrive as 1-byte bool or int32; sniff from the first word.
__device__ __forceinline__ bool tok_mask(const void* tm, int t, int mmode) {
    return mmode == 0 ? (((const unsigned char*)tm)[t] != 0)
                      : (((const unsigned int*)tm)[t] != 0u);
}

__global__ __launch_bounds__(256, 4)
void router_v5(const float* __restrict__ h,
               const float* __restrict__ W,
               const void* __restrict__ tmask,
               float* __restrict__ out)
{
    __shared__ float h_s[64][STR];            // 16.6 KB; pb aliases after compute
    __shared__ float w_s[64][STR];            // 16.6 KB; ls aliases after compute
    __shared__ unsigned long long mb[64];

    const int tid  = threadIdx.x;
    const int lane = tid & 63;
    const int wave = tid >> 6;
    const int tt   = tid & 15;                // token group (rows tt*4 .. tt*4+3)
    const int ee   = tid >> 4;                // expert group (rows ee*4 .. ee*4+3)
    const int t0   = blockIdx.x * 64;

    const unsigned int w0 = *(const unsigned int*)tmask;
    const int mmode = (w0 == 0x01010101u) ? 0 : 1;

    // strict sequential fp32 FMA per output, k ascending (np-ref-matching order)
    float acc[4][4];
#pragma unroll
    for (int i = 0; i < 4; ++i)
#pragma unroll
        for (int j = 0; j < 4; ++j) acc[i][j] = 0.f;

    const int sr = tid >> 4;                  // staging row base 0..15
    const int sc = (tid & 15) * 4;            // staging col 0..60

    for (int kc = 0; kc < DMOD; kc += KCH) {
        // ---- stage h tile (64x64) and W tile (64x64), coalesced ----
#pragma unroll
        for (int p = 0; p < 4; ++p) {
            const int row = sr + p * 16;
            *reinterpret_cast<float4*>(&h_s[row][sc]) =
                *reinterpret_cast<const float4*>(h + (size_t)(t0 + row) * DMOD + kc + sc);
            *reinterpret_cast<float4*>(&w_s[row][sc]) =
                *reinterpret_cast<const float4*>(W + ((size_t)row << 10) + kc + sc);
        }
        __syncthreads();

        // ---- compute: 4 tokens x 4 experts per thread ----
#pragma unroll 2
        for (int k = 0; k < KCH; k += 4) {
            float4 hv[4], wv[4];
#pragma unroll
            for (int i = 0; i < 4; ++i)
                hv[i] = *reinterpret_cast<const float4*>(&h_s[tt * 4 + i][k]);
#pragma unroll
            for (int j = 0; j < 4; ++j)
                wv[j] = *reinterpret_cast<const float4*>(&w_s[ee * 4 + j][k]);
#pragma unroll
            for (int i = 0; i < 4; ++i) {
#pragma unroll
                for (int j = 0; j < 4; ++j) {
                    float a = acc[i][j];
                    a = fmaf(hv[i].x, wv[j].x, a);
                    a = fmaf(hv[i].y, wv[j].y, a);
                    a = fmaf(hv[i].z, wv[j].z, a);
                    a = fmaf(hv[i].w, wv[j].w, a);
                    acc[i][j] = a;
                }
            }
        }
        __syncthreads();
    }

    // ---- stage logits to LDS (ls aliases w_s — dead after last barrier) ----
    float (*ls)[STR] = w_s;
    float (*pb)[STR] = h_s;

#pragma unroll
    for (int i = 0; i < 4; ++i)
#pragma unroll
        for (int j = 0; j < 4; ++j)
            ls[tt * 4 + i][ee * 4 + j] = acc[i][j];

    __syncthreads();

    const size_t P = (size_t)NTOK * NEXP;
    float* __restrict__ o_mask = out;
    float* __restrict__ o_prob = out + P;
    float* __restrict__ o_lc   = out + 2 * P;
    float* __restrict__ o_lsl  = out + 3 * P;
    const size_t base = (size_t)t0 * NEXP;

    // ---- coalesced writes of logits_clean / logits_sel ----
#pragma unroll
    for (int i = 0; i < 16; ++i) {
        const int f = i * 256 + tid;
        const int t = f >> 6, e = f & 63;
        const float lv = ls[t][e];
        const bool tmt = tok_mask(tmask, t0 + t, mmode);
        o_lc[base + f]  = lv;
        o_lsl[base + f] = tmt ? lv : -INFINITY;
    }

    // ---- epilogue: wave0, one token per lane; 8-pass selection-sort top-k ----
    if (wave == 0) {
        const int lt = lane;
        const bool tm = tok_mask(tmask, t0 + lt, mmode);

        unsigned long long bits = 0ULL;
        float m0 = -INFINITY;
        for (int r = 0; r < TOPK; ++r) {
            float bv = -INFINITY; int bi = 0;
            for (int e = 0; e < 64; ++e) {
                if ((bits >> e) & 1ULL) continue;
                const float x = ls[lt][e];
                if (x > bv) { bv = x; bi = e; }
            }
            bits |= 1ULL << bi;
            if (r == 0) m0 = bv;
        }

        float ssum = 0.f;
        for (int e = 0; e < 64; ++e)
            if ((bits >> e) & 1ULL) ssum += expf(ls[lt][e] - m0);
        const float inv = 1.0f / ssum;
        for (int e = 0; e < 64; ++e) {
            const bool sel = ((bits >> e) & 1ULL) != 0ULL;
            pb[lt][e] = (tm && sel) ? expf(ls[lt][e] - m0) * inv : 0.f;
        }
        mb[lt] = tm ? bits : 0ULL;
    }

    __syncthreads();

    // ---- coalesced writes of probs / mask ----
#pragma unroll
    for (int i = 0; i < 16; ++i) {
        const int f = i * 256 + tid;
        const int t = f >> 6, e = f & 63;
        o_prob[base + f] = pb[t][e];
        o_mask[base + f] = (float)((mb[t] >> e) & 1ULL);
    }
}

extern "C" void kernel_launch(void* const* d_in, const int* in_sizes, int n_in,
                              void* d_out, int out_size, void* d_ws, size_t ws_size,
                              hipStream_t stream)
{
    const float* h = (const float*)d_in[0];
    const float* W = (const float*)d_in[1];
    const void*  tmask = (const void*)d_in[2];
    float* out = (float*)d_out;

    hipLaunchKernelGGL(router_v5, dim3(NTOK / 64), dim3(256), 0, stream,
                       h, W, tmask, out);
}